// Round 5
// baseline (11.908 us; speedup 1.0000x reference)
//
#include <hip/hip_runtime.h>

// Problem constants (match reference)
#define BATCH       16
#define SEQ_N       1024
#define EMBED_DIM   256
#define NTILE       16     // n-values per block
#define LDS_STRIDE4 65     // float4 stride -> 260-float element stride (2-way read, free)

typedef float f32x4 __attribute__((ext_vector_type(4)));

// out[b][d][n] = embedding[seq[b][n]][d]
// One block: (b, n-tile of 16). 1024 blocks x 512 threads -> 4 blocks/CU,
// 32 waves/CU (occupancy max).
// NOTE: plain (cached) stores on purpose — output (16 MB) fits in L3, so
// across graph replays dirty lines are overwritten in-cache and HBM write
// traffic ~0. Nontemporal stores (R4) defeat this.
__global__ __launch_bounds__(512) void
embed_gather_transpose(const int* __restrict__ seq,
                       const float* __restrict__ emb,
                       float* __restrict__ out) {
    __shared__ f32x4 lds4[NTILE * LDS_STRIDE4];   // 16.6 KB
    const float* lds = reinterpret_cast<const float*>(lds4);

    const int b  = blockIdx.x >> 6;          // 64 tiles per batch
    const int n0 = (blockIdx.x & 63) << 4;   // *NTILE
    const int* seqb = seq + b * SEQ_N + n0;

    // ---- load phase: 16 rows x 64 float4 = 1024 float4, 2 per thread ----
    // f32x4 LDS writes -> ds_write_b128, conflict-free; global reads fully
    // coalesced (one wave reads one full 1KB row per iteration).
#pragma unroll
    for (int i = 0; i < 2; ++i) {
        const int flat = i * 512 + threadIdx.x;  // 0..1023
        const int nn   = flat >> 6;              // row in tile (64 float4/row)
        const int c4   = flat & 63;              // float4 column
        const int row  = seqb[nn];               // 64B line, L1 broadcast
        lds4[nn * LDS_STRIDE4 + c4] =
            reinterpret_cast<const f32x4*>(emb + (size_t)row * EMBED_DIM)[c4];
    }
    __syncthreads();

    // ---- store phase: 256 d x 4 float4 (16 n) = 1024 float4, 2 per thread ----
    // 4 consecutive lanes emit one contiguous 64B chunk per d; 64B-aligned.
    // Transpose read: bank = (4*nn + d) mod 32 -> 2 lanes/bank = free.
    float* outb = out + ((size_t)b * EMBED_DIM) * SEQ_N + n0;
#pragma unroll
    for (int i = 0; i < 2; ++i) {
        const int flat = i * 512 + threadIdx.x;  // 0..1023
        const int d    = flat >> 2;
        const int q    = flat & 3;               // float4 index within 16-n chunk
        const int nn   = q << 2;
        f32x4 v;
        v.x = lds[(nn + 0) * (LDS_STRIDE4 * 4) + d];
        v.y = lds[(nn + 1) * (LDS_STRIDE4 * 4) + d];
        v.z = lds[(nn + 2) * (LDS_STRIDE4 * 4) + d];
        v.w = lds[(nn + 3) * (LDS_STRIDE4 * 4) + d];
        reinterpret_cast<f32x4*>(outb + (size_t)d * SEQ_N)[q] = v;
    }
}

extern "C" void kernel_launch(void* const* d_in, const int* in_sizes, int n_in,
                              void* d_out, int out_size, void* d_ws, size_t ws_size,
                              hipStream_t stream) {
    const int*   seq = (const int*)d_in[0];
    const float* emb = (const float*)d_in[1];
    float*       out = (float*)d_out;

    const int grid = BATCH * (SEQ_N / NTILE);  // 16 * 64 = 1024 blocks
    embed_gather_transpose<<<grid, 512, 0, stream>>>(seq, emb, out);
}